// Round 2
// baseline (356.086 us; speedup 1.0000x reference)
//
#include <hip/hip_runtime.h>
#include <math.h>

#define R_ 4
#define B_ 16
#define HQ_ 32
#define HKV_ 2
#define G_ 16
#define D_ 128
#define S_ 32
#define L_ 2048
#define P_ 32768
#define TS_ 64    // max rows per split tile (per <= 64)
#define NEGINF (-INFINITY)

// ws layout (floats), CH = S_/NSPL chunks:
//   lse_split [R][B][HKV][S][G]            = 65536
//   chunk_m   [R][B][HKV][CH][G]
//   chunk_acc [R][B][HKV][CH][G][D]

template<int NSPL>
__global__ __launch_bounds__(256) void fd_stage1(
    const float* __restrict__ q, const float* __restrict__ kc,
    const float* __restrict__ vc, const int* __restrict__ bt,
    const int* __restrict__ lens,
    float* __restrict__ lse_split, float* __restrict__ chunk_m,
    float* __restrict__ chunk_acc)
{
  constexpr int CH = S_ / NSPL;
  const int t    = threadIdx.x;
  const int blk  = blockIdx.x;
  const int c    = blk % CH;
  const int rest = blk / CH;
  const int hkv  = rest & 1;
  const int b    = (rest >> 1) & 15;
  const int r    = rest >> 5;

  const int len = lens[r*B_ + b];
  const int per = (len + S_ - 1) >> 5;   // ceil(len/32), 2..64

  __shared__ float q_s[G_][D_+4];
  __shared__ float k_s[TS_][D_+4];
  __shared__ float p_s[G_][TS_];
  __shared__ float alpha_s[G_];
  __shared__ int   page_s[TS_];

  // stage q tile for this (b, hkv): 16 heads x 128, fully coalesced
  {
    const float* qb = q + (b*HQ_ + hkv*G_)*D_;
    int f4 = t;
    #pragma unroll
    for (int i = 0; i < 2; ++i, f4 += 256) {
      int g = f4 >> 5, dd = (f4 & 31) * 4;
      *(float4*)&q_s[g][dd] = *(const float4*)&qb[g*D_ + dd];
    }
  }

  // score-phase mapping: thread owns (g = sg, n in {nl, nl+16, nl+32, nl+48})
  const int sg = t >> 4;
  const int nl = t & 15;
  // PV mapping: thread owns (d4..d4+3) x heads {gp, gp+8}
  const int d4 = (t & 31) * 4;
  const int gp = t >> 5;

  float  m_run = NEGINF;                    // per sg (redundant across its 16 lanes)
  float4 acc0 = make_float4(0.f,0.f,0.f,0.f);
  float4 acc1 = make_float4(0.f,0.f,0.f,0.f);

  const int* btb   = bt + (r*B_ + b)*L_;
  const int kvbase = r*(P_*HKV_*D_) + hkv*D_;   // element offset; < 2^31/4 ok
  float* lse_out = lse_split + ((r*B_ + b)*HKV_ + hkv)*(S_*G_);

  for (int j = 0; j < NSPL; ++j) {
    const int s  = c*NSPL + j;
    const int n0 = s*per;
    const int tn = min(per, len - n0);      // block-uniform
    if (tn <= 0) {
      if (t < G_) lse_out[s*G_ + t] = NEGINF;  // empty split -> -inf
      continue;                               // final writes emit m=-inf, acc=0
    }
    __syncthreads();                         // protect page_s/p_s from prior tile PV
    if (t < tn) page_s[t] = btb[n0 + t];
    __syncthreads();
    // stage K rows [0, tn): 8 rows in parallel, 32 lanes x float4 per row
    for (int row = t >> 5; row < tn; row += 8) {
      const float4 kx = *(const float4*)&kc[kvbase + page_s[row]*(HKV_*D_) + ((t & 31)*4)];
      *(float4*)&k_s[row][(t & 31)*4] = kx;
    }
    __syncthreads();

    // scores: up to 4 dots of 128 per thread; KN tiers (block-uniform) skip
    // k-row groups entirely beyond ceil(tn/16) -- saves the LDS pipe.
    const int KN = (tn + 15) >> 4;           // 1..4
    float s0 = 0.f, s1 = 0.f, s2 = 0.f, s3 = 0.f;
    #pragma unroll 4
    for (int d = 0; d < D_; d += 4) {
      const float4 q4 = *(const float4*)&q_s[sg][d];
      const float4 k0 = *(const float4*)&k_s[nl][d];
      s0 += q4.x*k0.x + q4.y*k0.y + q4.z*k0.z + q4.w*k0.w;
      if (KN > 1) {
        const float4 k1 = *(const float4*)&k_s[nl + 16][d];
        s1 += q4.x*k1.x + q4.y*k1.y + q4.z*k1.z + q4.w*k1.w;
      }
      if (KN > 2) {
        const float4 k2 = *(const float4*)&k_s[nl + 32][d];
        s2 += q4.x*k2.x + q4.y*k2.y + q4.z*k2.z + q4.w*k2.w;
      }
      if (KN > 3) {
        const float4 k3 = *(const float4*)&k_s[nl + 48][d];
        s3 += q4.x*k3.x + q4.y*k3.y + q4.z*k3.z + q4.w*k3.w;
      }
    }
    const float sc = 0.08838834764831845f;   // 128^-0.5
    float sv0 = (nl      < tn) ? s0*sc : NEGINF;
    float sv1 = (nl + 16 < tn) ? s1*sc : NEGINF;
    float sv2 = (nl + 32 < tn) ? s2*sc : NEGINF;
    float sv3 = (nl + 48 < tn) ? s3*sc : NEGINF;

    // per-(g) tile max + sumexp across the 16 lanes of this g
    float pm = fmaxf(fmaxf(sv0, sv1), fmaxf(sv2, sv3));
    #pragma unroll
    for (int off = 1; off < 16; off <<= 1)
      pm = fmaxf(pm, __shfl_xor(pm, off));
    float ps = __expf(sv0 - pm) + __expf(sv1 - pm) + __expf(sv2 - pm) + __expf(sv3 - pm);
    #pragma unroll
    for (int off = 1; off < 16; off <<= 1)
      ps += __shfl_xor(ps, off);
    const float lse  = pm + __logf(ps);      // exact per-split lse (tn>=1 -> finite)
    const float newm = (NSPL > 1) ? fmaxf(m_run, pm) : pm;
    if (nl == 0) {
      lse_out[s*G_ + sg] = lse;
      if (NSPL > 1) alpha_s[sg] = __expf(m_run - newm);
    }
    m_run = newm;
    p_s[sg][nl] = __expf(sv0 - newm);        // invalid n -> exp(-inf) = 0
    if (KN > 1) p_s[sg][nl + 16] = __expf(sv1 - newm);
    if (KN > 2) p_s[sg][nl + 32] = __expf(sv2 - newm);
    if (KN > 3) p_s[sg][nl + 48] = __expf(sv3 - newm);
    __syncthreads();                          // p_s (and alpha_s) ready

    // PV: V read straight from global (512B rows, L1/L2 absorb the 2x lane dup)
    if (NSPL > 1) {
      const float a0 = alpha_s[gp], a1 = alpha_s[gp + 8];
      acc0.x *= a0; acc0.y *= a0; acc0.z *= a0; acc0.w *= a0;
      acc1.x *= a1; acc1.y *= a1; acc1.z *= a1; acc1.w *= a1;
    }
    #pragma unroll 4
    for (int n = 0; n < tn; ++n) {
      const float4 v4 = *(const float4*)&vc[kvbase + page_s[n]*(HKV_*D_) + d4];
      const float p0 = p_s[gp][n], p1 = p_s[gp + 8][n];
      acc0.x += p0*v4.x; acc0.y += p0*v4.y; acc0.z += p0*v4.z; acc0.w += p0*v4.w;
      acc1.x += p1*v4.x; acc1.y += p1*v4.y; acc1.z += p1*v4.z; acc1.w += p1*v4.w;
    }
  }

  // chunk outputs (written unconditionally; empty chunk -> m=-inf, acc=0)
  if (nl == 0)
    chunk_m[(((r*B_ + b)*HKV_ + hkv)*CH + c)*G_ + sg] = m_run;
  float* ca = chunk_acc + (size_t)((((r*B_ + b)*HKV_ + hkv)*CH + c)*G_) * D_;
  *(float4*)&ca[gp*D_ + d4]       = acc0;
  *(float4*)&ca[(gp + 8)*D_ + d4] = acc1;
}

__global__ __launch_bounds__(128) void fd_stage2(
    const float* __restrict__ lse_split, const float* __restrict__ chunk_m,
    const float* __restrict__ chunk_acc, float* __restrict__ out, int CH)
{
  const int bh  = blockIdx.x;          // b*32 + h
  const int b   = bh >> 5, h = bh & 31;
  const int hkv = h >> 4, g = h & 15;
  const int d   = threadIdx.x;

  float m_r[R_], lse_r[R_];
  #pragma unroll
  for (int r = 0; r < R_; ++r) {
    const float* ls = lse_split + ((r*B_ + b)*HKV_ + hkv)*(S_*G_) + g;
    float m = NEGINF;
    #pragma unroll
    for (int s2 = 0; s2 < S_; ++s2) m = fmaxf(m, ls[s2*G_]);
    float sum = 0.f;
    #pragma unroll
    for (int s2 = 0; s2 < S_; ++s2) sum += __expf(ls[s2*G_] - m);  // -inf entries -> 0
    m_r[r]   = m;                       // len>=64 -> split 0 nonempty -> finite
    lse_r[r] = m + __logf(sum);
  }
  const float M = fmaxf(fmaxf(lse_r[0], lse_r[1]), fmaxf(lse_r[2], lse_r[3]));
  float denom = 0.f, o = 0.f;
  #pragma unroll
  for (int r = 0; r < R_; ++r) {
    const float w = __expf(lse_r[r] - M);
    denom += w;
    const float* cm = chunk_m  + (((r*B_ + b)*HKV_ + hkv)*CH)*G_ + g;
    const float* ca = chunk_acc + (size_t)((((r*B_ + b)*HKV_ + hkv)*CH)*G_ + g) * D_ + d;
    float a = 0.f;
    for (int cc2 = 0; cc2 < CH; ++cc2)
      a += __expf(cm[cc2*G_] - m_r[r]) * ca[(size_t)cc2 * (G_*D_)];  // empty chunk: 0 * 0
    o += w * a;   // faithful: acc_r is UNNORMALIZED, weighted by exp(lse_r - M)
  }
  out[(size_t)bh*D_ + d] = o / denom;
}

extern "C" void kernel_launch(void* const* d_in, const int* in_sizes, int n_in,
                              void* d_out, int out_size, void* d_ws, size_t ws_size,
                              hipStream_t stream) {
  const float* q   = (const float*)d_in[0];
  const float* kc  = (const float*)d_in[1];
  const float* vc  = (const float*)d_in[2];
  const int*   bt  = (const int*)d_in[3];
  const int*   len = (const int*)d_in[4];
  float* out = (float*)d_out;
  float* ws  = (float*)d_ws;

  // prefer 1 split per block (CH=32) when ws is big enough for the 34 MB acc
  const size_t lse_f = (size_t)R_*B_*HKV_*S_*G_;                 // 65536
  const size_t need32 = (lse_f + (size_t)R_*B_*HKV_*32*G_ +
                         (size_t)R_*B_*HKV_*32*G_*D_) * 4;
  if (ws_size >= need32) {
    const int CH = 32;
    float* lse_split = ws;
    float* chunk_m   = ws + lse_f;
    float* chunk_acc = chunk_m + (size_t)R_*B_*HKV_*CH*G_;
    fd_stage1<1><<<dim3(R_*B_*HKV_*CH), dim3(256), 0, stream>>>(
        q, kc, vc, bt, len, lse_split, chunk_m, chunk_acc);
    fd_stage2<<<dim3(B_*HQ_), dim3(128), 0, stream>>>(
        lse_split, chunk_m, chunk_acc, out, CH);
  } else {
    const int CH = 8;
    float* lse_split = ws;
    float* chunk_m   = ws + lse_f;
    float* chunk_acc = chunk_m + (size_t)R_*B_*HKV_*CH*G_;
    fd_stage1<4><<<dim3(R_*B_*HKV_*CH), dim3(256), 0, stream>>>(
        q, kc, vc, bt, len, lse_split, chunk_m, chunk_acc);
    fd_stage2<<<dim3(B_*HQ_), dim3(128), 0, stream>>>(
        lse_split, chunk_m, chunk_acc, out, CH);
  }
}

// Round 3
// 307.653 us; speedup vs baseline: 1.1574x; 1.1574x over previous
//
#include <hip/hip_runtime.h>
#include <math.h>

#define R_ 4
#define B_ 16
#define HQ_ 32
#define HKV_ 2
#define G_ 16
#define D_ 128
#define S_ 32
#define L_ 2048
#define P_ 32768
#define TS_ 64
#define KSTR 136   // halves per k_s/q_s row: 272B, 16B-aligned, 2-way banks (free)
#define PSTR 18    // floats per p_s row: even stride so float2 reads are 8B-aligned
#define NEGINF (-INFINITY)

typedef _Float16 h2 __attribute__((ext_vector_type(2)));
typedef _Float16 h4 __attribute__((ext_vector_type(4)));
typedef _Float16 h8 __attribute__((ext_vector_type(8)));

#if defined(__has_builtin)
#  if __has_builtin(__builtin_amdgcn_fdot2)
#    define FDOT2(a,b,c) __builtin_amdgcn_fdot2((a),(b),(c),false)
#  endif
#endif
#ifndef FDOT2
static __device__ __forceinline__ float fdot2_sw(h2 a, h2 b, float c) {
  return c + (float)a.x*(float)b.x + (float)a.y*(float)b.y;
}
#  define FDOT2(a,b,c) fdot2_sw((a),(b),(c))
#endif

// ws layout:
//   lse_split [R][B][HKV][S][G]  float   = 65536 f
//   chunk_m   [R][B][HKV][S][G]  float   = 65536 f
//   chunk_acc [R][B][HKV][S][G][D] half  = 8388608 h (16.8 MB)

__global__ __launch_bounds__(256, 6) void fd_stage1(
    const float* __restrict__ q, const float* __restrict__ kc,
    const float* __restrict__ vc, const int* __restrict__ bt,
    const int* __restrict__ lens,
    float* __restrict__ lse_split, float* __restrict__ chunk_m,
    _Float16* __restrict__ chunk_acc)
{
  const int t   = threadIdx.x;
  const int blk = blockIdx.x;
  const int s   = blk & 31;
  const int hkv = (blk >> 5) & 1;
  const int b   = (blk >> 6) & 15;
  const int r   = blk >> 10;

  const int len = lens[r*B_ + b];
  const int per = (len + 31) >> 5;        // ceil(len/32), 2..64
  const int n0  = s*per;
  const int tn  = min(per, len - n0);     // block-uniform

  float* lse_out = lse_split + ((r*B_ + b)*HKV_ + hkv)*(S_*G_);
  const int cmbase = (((r*B_ + b)*HKV_ + hkv)*S_ + s)*G_;
  _Float16* ca = chunk_acc + (size_t)(((r*B_ + b)*HKV_ + hkv)*S_ + s)*(G_*D_);

  if (tn <= 0) {                          // empty split: -inf lse/m, zero acc
    if (t < G_) { lse_out[s*G_ + t] = NEGINF; chunk_m[cmbase + t] = NEGINF; }
    h8 z = {(_Float16)0,(_Float16)0,(_Float16)0,(_Float16)0,
            (_Float16)0,(_Float16)0,(_Float16)0,(_Float16)0};
    *(h8*)&ca[t*8] = z;                   // 256 thr x 8 halves = G_*D_
    return;
  }

  __shared__ _Float16 q_s[G_][KSTR];
  __shared__ _Float16 k_s[TS_][KSTR];
  __shared__ float    p_s[TS_][PSTR];

  // stage Q (fp32 -> fp16): 16 heads x 128, coalesced
  {
    const float* qb = q + (b*HQ_ + hkv*G_)*D_;
    int f4 = t;
    #pragma unroll
    for (int i = 0; i < 2; ++i, f4 += 256) {
      const int g = f4 >> 5, dd = (f4 & 31)*4;
      const float4 v = *(const float4*)&qb[g*D_ + dd];
      h4 hv; hv.x=(_Float16)v.x; hv.y=(_Float16)v.y; hv.z=(_Float16)v.z; hv.w=(_Float16)v.w;
      *(h4*)&q_s[g][dd] = hv;
    }
  }

  const int* btb   = bt + (r*B_ + b)*L_;
  const int kvbase = r*(P_*HKV_*D_) + hkv*D_;

  // stage K rows (fp32 -> fp16): 8 rows in parallel, 32 lanes x 4 elems
  {
    const int lane = t & 31, rw = t >> 5;
    for (int row = rw; row < tn; row += 8) {
      const int pg = btb[n0 + row];       // 32-lane broadcast, L1/L2
      const float4 v = *(const float4*)&kc[kvbase + pg*(HKV_*D_) + lane*4];
      h4 hv; hv.x=(_Float16)v.x; hv.y=(_Float16)v.y; hv.z=(_Float16)v.z; hv.w=(_Float16)v.w;
      *(h4*)&k_s[row][lane*4] = hv;
    }
  }
  __syncthreads();

  // scores: thread (sg, nl) owns rows {nl, nl+16, nl+32, nl+48}; KN tiers skip
  // absent row groups (block-uniform).
  const int sg = t >> 4, nl = t & 15;
  const int KN = (tn + 15) >> 4;          // 1..4
  float s0 = 0.f, s1 = 0.f, s2 = 0.f, s3 = 0.f;
  #pragma unroll 4
  for (int d8 = 0; d8 < 16; ++d8) {
    const h8 q8 = *(const h8*)&q_s[sg][d8*8];
    const h8 k0 = *(const h8*)&k_s[nl][d8*8];
    #pragma unroll
    for (int j = 0; j < 4; ++j) s0 = FDOT2(((const h2*)&q8)[j], ((const h2*)&k0)[j], s0);
    if (KN > 1) {
      const h8 k1 = *(const h8*)&k_s[nl + 16][d8*8];
      #pragma unroll
      for (int j = 0; j < 4; ++j) s1 = FDOT2(((const h2*)&q8)[j], ((const h2*)&k1)[j], s1);
    }
    if (KN > 2) {
      const h8 k2 = *(const h8*)&k_s[nl + 32][d8*8];
      #pragma unroll
      for (int j = 0; j < 4; ++j) s2 = FDOT2(((const h2*)&q8)[j], ((const h2*)&k2)[j], s2);
    }
    if (KN > 3) {
      const h8 k3 = *(const h8*)&k_s[nl + 48][d8*8];
      #pragma unroll
      for (int j = 0; j < 4; ++j) s3 = FDOT2(((const h2*)&q8)[j], ((const h2*)&k3)[j], s3);
    }
  }
  const float sc = 0.08838834764831845f;  // 128^-0.5
  const float sv0 = (nl      < tn) ? s0*sc : NEGINF;
  const float sv1 = (nl + 16 < tn) ? s1*sc : NEGINF;
  const float sv2 = (nl + 32 < tn) ? s2*sc : NEGINF;
  const float sv3 = (nl + 48 < tn) ? s3*sc : NEGINF;

  // per-g max + sumexp across the 16 lanes of this g
  float pm = fmaxf(fmaxf(sv0, sv1), fmaxf(sv2, sv3));
  #pragma unroll
  for (int off = 1; off < 16; off <<= 1) pm = fmaxf(pm, __shfl_xor(pm, off));
  float ps = __expf(sv0 - pm) + __expf(sv1 - pm) + __expf(sv2 - pm) + __expf(sv3 - pm);
  #pragma unroll
  for (int off = 1; off < 16; off <<= 1) ps += __shfl_xor(ps, off);

  if (nl == 0) {
    lse_out[s*G_ + sg] = pm + __logf(ps);   // exact per-split lse
    chunk_m[cmbase + sg] = pm;              // split max (== running max, NSPL=1)
  }

  // p transposed: p_s[n][g], invalid rows -> 0
  p_s[nl][sg] = __expf(sv0 - pm);
  if (KN > 1) p_s[nl + 16][sg] = __expf(sv1 - pm);
  if (KN > 2) p_s[nl + 32][sg] = __expf(sv2 - pm);
  if (KN > 3) p_s[nl + 48][sg] = __expf(sv3 - pm);
  __syncthreads();

  // PV: thread owns head pair (g2, g2+1) x dims d4..d4+3; V straight from global
  const int d4 = (t & 31)*4;
  const int g2 = (t >> 5)*2;
  float4 a0 = make_float4(0.f,0.f,0.f,0.f);
  float4 a1 = make_float4(0.f,0.f,0.f,0.f);
  #pragma unroll 4
  for (int n = 0; n < tn; ++n) {
    const int pg = btb[n0 + n];             // broadcast
    const float4 v4 = *(const float4*)&vc[kvbase + pg*(HKV_*D_) + d4];
    const float2 pp = *(const float2*)&p_s[n][g2];
    a0.x += pp.x*v4.x; a0.y += pp.x*v4.y; a0.z += pp.x*v4.z; a0.w += pp.x*v4.w;
    a1.x += pp.y*v4.x; a1.y += pp.y*v4.y; a1.z += pp.y*v4.z; a1.w += pp.y*v4.w;
  }

  h4 o0; o0.x=(_Float16)a0.x; o0.y=(_Float16)a0.y; o0.z=(_Float16)a0.z; o0.w=(_Float16)a0.w;
  h4 o1; o1.x=(_Float16)a1.x; o1.y=(_Float16)a1.y; o1.z=(_Float16)a1.z; o1.w=(_Float16)a1.w;
  *(h4*)&ca[g2*D_ + d4]       = o0;
  *(h4*)&ca[(g2 + 1)*D_ + d4] = o1;
}

__global__ __launch_bounds__(128) void fd_stage2(
    const float* __restrict__ lse_split, const float* __restrict__ chunk_m,
    const _Float16* __restrict__ chunk_acc, float* __restrict__ out)
{
  const int bh  = blockIdx.x;          // b*32 + h
  const int b   = bh >> 5, h = bh & 31;
  const int hkv = h >> 4, g = h & 15;
  const int d   = threadIdx.x;

  float m_r[R_], lse_r[R_];
  #pragma unroll
  for (int r = 0; r < R_; ++r) {
    const float* ls = lse_split + ((r*B_ + b)*HKV_ + hkv)*(S_*G_) + g;
    float m = NEGINF;
    #pragma unroll 8
    for (int s2 = 0; s2 < S_; ++s2) m = fmaxf(m, ls[s2*G_]);
    float sum = 0.f;
    #pragma unroll 8
    for (int s2 = 0; s2 < S_; ++s2) sum += __expf(ls[s2*G_] - m);
    m_r[r]   = m;
    lse_r[r] = m + __logf(sum);
  }
  const float M = fmaxf(fmaxf(lse_r[0], lse_r[1]), fmaxf(lse_r[2], lse_r[3]));
  float denom = 0.f, o = 0.f;
  #pragma unroll
  for (int r = 0; r < R_; ++r) {
    const float w = __expf(lse_r[r] - M);
    denom += w;
    const float* cm = chunk_m + (((r*B_ + b)*HKV_ + hkv)*S_)*G_ + g;
    const _Float16* ca = chunk_acc
        + (size_t)(((r*B_ + b)*HKV_ + hkv)*S_)*(G_*D_) + g*D_ + d;
    float a = 0.f;
    #pragma unroll 8
    for (int c = 0; c < S_; ++c)
      a += __expf(cm[c*G_] - m_r[r]) * (float)ca[(size_t)c*(G_*D_)];
    o += w * a;   // faithful: acc_r UNNORMALIZED, weighted by exp(lse_r - M)
  }
  out[(size_t)bh*D_ + d] = o / denom;
}

extern "C" void kernel_launch(void* const* d_in, const int* in_sizes, int n_in,
                              void* d_out, int out_size, void* d_ws, size_t ws_size,
                              hipStream_t stream) {
  const float* q   = (const float*)d_in[0];
  const float* kc  = (const float*)d_in[1];
  const float* vc  = (const float*)d_in[2];
  const int*   bt  = (const int*)d_in[3];
  const int*   len = (const int*)d_in[4];
  float* out = (float*)d_out;
  float* ws  = (float*)d_ws;

  const size_t lse_f = (size_t)R_*B_*HKV_*S_*G_;   // 65536
  float*    lse_split = ws;
  float*    chunk_m   = ws + lse_f;
  _Float16* chunk_acc = (_Float16*)(ws + 2*lse_f);

  fd_stage1<<<dim3(R_*B_*HKV_*S_), dim3(256), 0, stream>>>(
      q, kc, vc, bt, len, lse_split, chunk_m, chunk_acc);
  fd_stage2<<<dim3(B_*HQ_), dim3(128), 0, stream>>>(
      lse_split, chunk_m, chunk_acc, out);
}